// Round 1
// baseline (418.779 us; speedup 1.0000x reference)
//
#include <hip/hip_runtime.h>

#define BB 2
#define SS 2048
#define DD 1024
#define HH 16
#define DHH 64

typedef _Float16 f16;
typedef f16 f16x8 __attribute__((ext_vector_type(8)));
typedef f16 f16x4 __attribute__((ext_vector_type(4)));
typedef float f32x4 __attribute__((ext_vector_type(4)));
typedef float fvec4 __attribute__((ext_vector_type(4)));

static __device__ __forceinline__ f32x4 mfma16(f16x8 a, f16x8 b, f32x4 c) {
    return __builtin_amdgcn_mfma_f32_16x16x32_f16(a, b, c, 0, 0, 0);
}

// ---------------- weight transpose + f32->f16 convert ----------------
// Wt[n][k] = (f16) W[k][n], 1024x1024, 4 matrices via blockIdx.z
__global__ __launch_bounds__(256) void wtrans_kernel(
    const float* __restrict__ w0, const float* __restrict__ w1,
    const float* __restrict__ w2, const float* __restrict__ w3,
    f16* __restrict__ o0, f16* __restrict__ o1,
    f16* __restrict__ o2, f16* __restrict__ o3)
{
    const float* src; f16* dst;
    switch (blockIdx.z) {
        case 0:  src = w0; dst = o0; break;
        case 1:  src = w1; dst = o1; break;
        case 2:  src = w2; dst = o2; break;
        default: src = w3; dst = o3; break;
    }
    __shared__ float t[64][65];
    const int tid = threadIdx.x;
    const int n0 = blockIdx.x * 64, k0 = blockIdx.y * 64;
    const int r = tid >> 4, c4 = (tid & 15) * 4;
    #pragma unroll
    for (int p = 0; p < 4; ++p) {
        int row = r + p * 16;
        fvec4 v = *(const fvec4*)&src[(size_t)(k0 + row) * DD + n0 + c4];
        #pragma unroll
        for (int j = 0; j < 4; ++j) t[row][c4 + j] = v[j];
    }
    __syncthreads();
    #pragma unroll
    for (int p = 0; p < 4; ++p) {
        int row = r + p * 16;  // n-local
        f16x4 v;
        #pragma unroll
        for (int j = 0; j < 4; ++j) v[j] = (f16)t[c4 + j][row];
        *(f16x4*)&dst[(size_t)(n0 + row) * DD + k0 + c4] = v;
    }
}

// ---------------- 128x128-tile GEMM: C[m][n] = sum_k A[m][k] * Bt[n][k] ----
// A_F32: A is f32 (converted in staging) else f16.
// OUT_MODE 0: f16 out, layout [B,H,S,DH]   (q, k)
// OUT_MODE 1: f16 out, layout [B,H,DH,S]   (v transposed)
// OUT_MODE 2: f32 out + bias, flat [M,N]   (final projection)
template<int A_F32, int OUT_MODE>
__global__ __launch_bounds__(256) void gemm128(
    const void* __restrict__ Aptr, const f16* __restrict__ Bt,
    const float* __restrict__ bias, void* __restrict__ Cptr)
{
    const int K = DD;
    const int m0 = blockIdx.y * 128, n0 = blockIdx.x * 128;
    const int tid = threadIdx.x, lane = tid & 63;
    const int wm = (tid >> 7) & 1, wn = (tid >> 6) & 1;
    const int ln = lane & 15, lg = lane >> 4;

    __shared__ f16 As[128][72];
    __shared__ f16 Bs[128][72];

    f32x4 acc[4][4] = {};

    const int sr = tid >> 3;         // 0..31
    const int sc = (tid & 7) * 8;    // 0..56

    for (int k0 = 0; k0 < K; k0 += 64) {
        #pragma unroll
        for (int p = 0; p < 4; ++p) {
            int row = sr + p * 32;
            if (A_F32) {
                const float* s = (const float*)Aptr + (size_t)(m0 + row) * K + k0 + sc;
                fvec4 x0 = *(const fvec4*)s;
                fvec4 x1 = *(const fvec4*)(s + 4);
                f16x8 v;
                #pragma unroll
                for (int j = 0; j < 4; ++j) { v[j] = (f16)x0[j]; v[j + 4] = (f16)x1[j]; }
                *(f16x8*)&As[row][sc] = v;
            } else {
                *(f16x8*)&As[row][sc] =
                    *(const f16x8*)((const f16*)Aptr + (size_t)(m0 + row) * K + k0 + sc);
            }
            *(f16x8*)&Bs[row][sc] =
                *(const f16x8*)(Bt + (size_t)(n0 + row) * K + k0 + sc);
        }
        __syncthreads();
        #pragma unroll
        for (int ks = 0; ks < 2; ++ks) {
            f16x8 af[4], bf[4];
            #pragma unroll
            for (int i = 0; i < 4; ++i) {
                af[i] = *(const f16x8*)&As[wm * 64 + i * 16 + ln][ks * 32 + lg * 8];
                bf[i] = *(const f16x8*)&Bs[wn * 64 + i * 16 + ln][ks * 32 + lg * 8];
            }
            #pragma unroll
            for (int i = 0; i < 4; ++i)
                #pragma unroll
                for (int j = 0; j < 4; ++j)
                    acc[i][j] = mfma16(af[i], bf[j], acc[i][j]);
        }
        __syncthreads();
    }

    #pragma unroll
    for (int i = 0; i < 4; ++i) {
        #pragma unroll
        for (int j = 0; j < 4; ++j) {
            if (OUT_MODE == 1) {
                int m = m0 + wm * 64 + i * 16 + lg * 4;
                int n = n0 + wn * 64 + j * 16 + ln;
                int b = m >> 11, s = m & (SS - 1);
                int h = n >> 6, dh = n & 63;
                f16x4 v4;
                #pragma unroll
                for (int v = 0; v < 4; ++v) v4[v] = (f16)acc[i][j][v];
                *(f16x4*)&((f16*)Cptr)[((size_t)((b * HH + h) * DHH + dh)) * SS + s] = v4;
            } else {
                #pragma unroll
                for (int v = 0; v < 4; ++v) {
                    int m = m0 + wm * 64 + i * 16 + lg * 4 + v;
                    int n = n0 + wn * 64 + j * 16 + ln;
                    float val = acc[i][j][v];
                    if (OUT_MODE == 2) {
                        ((float*)Cptr)[(size_t)m * DD + n] = val + bias[n];
                    } else {
                        int b = m >> 11, s = m & (SS - 1);
                        int h = n >> 6, dh = n & 63;
                        ((f16*)Cptr)[((size_t)((b * HH + h) * SS + s)) * DHH + dh] = (f16)val;
                    }
                }
            }
        }
    }
}

// ---------------- fused attention ----------------
// grid: 512 blocks (bijective XCD swizzle), block = 512 threads = 8 waves.
// Each block: one (b,h), 128 q-rows. Each wave: 16 q-rows.
__global__ __launch_bounds__(512) void attn_kernel(
    const f16* __restrict__ qg, const f16* __restrict__ kg, const f16* __restrict__ vtg,
    const float* __restrict__ maskg, const float* __restrict__ peng,
    float* __restrict__ attn_out, f16* __restrict__ ctx_out)
{
    // bijective XCD swizzle: 512 % 8 == 0
    const int bid = blockIdx.x;
    const int wg = (bid & 7) * 64 + (bid >> 3);
    const int bh = wg >> 4;            // 0..31
    const int b = bh >> 4, h = bh & 15;
    const int q0 = (wg & 15) * 128;

    const int tid = threadIdx.x, lane = tid & 63, wv = tid >> 6;
    const int ln = lane & 15, lg = lane >> 4;

    __shared__ f16 Ks[128][72];
    __shared__ f16 Vt[64][136];
    __shared__ f16 Ps[128][72];
    __shared__ float tab[SS];
    __shared__ float mrow[SS];

    for (int i = tid; i < SS; i += 512) {
        tab[i]  = log1pf(peng[i]);              // pen row 0 = d/S  (Toeplitz)
        mrow[i] = maskg[b * SS + i] * (-1e9f);
    }

    const f16* qbase = qg + ((size_t)bh * SS + q0 + wv * 16 + ln) * DHH;
    f16x8 aq0 = *(const f16x8*)(qbase + lg * 8);
    f16x8 aq1 = *(const f16x8*)(qbase + 32 + lg * 8);

    __syncthreads();

    const int qi_s = q0 + wv * 16 + lg * 4;  // + v

    float mrun[4], lrun[4];
    #pragma unroll
    for (int v = 0; v < 4; ++v) { mrun[v] = -3e38f; lrun[v] = 0.f; }

    const int str = tid >> 3,  stc = (tid & 7) * 8;    // K staging
    const int vtr = tid >> 4,  vtc = (tid & 15) * 8;   // Vt staging

    // ---- pass 1: online (m, l) ----
    for (int kt = 0; kt < 16; ++kt) {
        const f16* ksrc = kg + ((size_t)bh * SS + kt * 128) * DHH;
        #pragma unroll
        for (int p = 0; p < 2; ++p)
            *(f16x8*)&Ks[str + p * 64][stc] =
                *(const f16x8*)(ksrc + (size_t)(str + p * 64) * DHH + stc);
        __syncthreads();

        f32x4 sfr[8];
        #pragma unroll
        for (int sub = 0; sub < 8; ++sub) {
            f32x4 sa = {0.f, 0.f, 0.f, 0.f};
            sa = mfma16(aq0, *(const f16x8*)&Ks[sub * 16 + ln][lg * 8], sa);
            sa = mfma16(aq1, *(const f16x8*)&Ks[sub * 16 + ln][32 + lg * 8], sa);
            const int kj = kt * 128 + sub * 16 + ln;
            const float fix = mrow[kj];
            #pragma unroll
            for (int v = 0; v < 4; ++v) {
                int d = qi_s + v - kj; d = d < 0 ? -d : d;
                sa[v] = sa[v] * 0.125f - tab[d] + fix;
            }
            sfr[sub] = sa;
        }
        #pragma unroll
        for (int v = 0; v < 4; ++v) {
            float mx = sfr[0][v];
            #pragma unroll
            for (int sub = 1; sub < 8; ++sub) mx = fmaxf(mx, sfr[sub][v]);
            #pragma unroll
            for (int off = 1; off < 16; off <<= 1) mx = fmaxf(mx, __shfl_xor(mx, off));
            float mnew = fmaxf(mrun[v], mx);
            float sum = 0.f;
            #pragma unroll
            for (int sub = 0; sub < 8; ++sub) sum += __expf(sfr[sub][v] - mnew);
            #pragma unroll
            for (int off = 1; off < 16; off <<= 1) sum += __shfl_xor(sum, off);
            lrun[v] = lrun[v] * __expf(mrun[v] - mnew) + sum;
            mrun[v] = mnew;
        }
        __syncthreads();
    }

    float rinv[4];
    #pragma unroll
    for (int v = 0; v < 4; ++v) rinv[v] = 1.f / lrun[v];

    f32x4 cacc[4] = {};

    // ---- pass 2: recompute, normalize, store attn, PV ----
    for (int kt = 0; kt < 16; ++kt) {
        const f16* ksrc = kg + ((size_t)bh * SS + kt * 128) * DHH;
        #pragma unroll
        for (int p = 0; p < 2; ++p)
            *(f16x8*)&Ks[str + p * 64][stc] =
                *(const f16x8*)(ksrc + (size_t)(str + p * 64) * DHH + stc);
        const f16* vsrc = vtg + (size_t)bh * DHH * SS + kt * 128;
        #pragma unroll
        for (int p = 0; p < 2; ++p)
            *(f16x8*)&Vt[vtr + p * 32][vtc] =
                *(const f16x8*)(vsrc + (size_t)(vtr + p * 32) * SS + vtc);
        __syncthreads();

        #pragma unroll
        for (int half = 0; half < 2; ++half) {
            #pragma unroll
            for (int s4 = 0; s4 < 4; ++s4) {
                const int sub = half * 4 + s4;
                f32x4 sa = {0.f, 0.f, 0.f, 0.f};
                sa = mfma16(aq0, *(const f16x8*)&Ks[sub * 16 + ln][lg * 8], sa);
                sa = mfma16(aq1, *(const f16x8*)&Ks[sub * 16 + ln][32 + lg * 8], sa);
                const int kj = kt * 128 + sub * 16 + ln;
                const float fix = mrow[kj];
                float* arow = attn_out + (size_t)(bh * SS + q0 + wv * 16 + lg * 4) * SS + kj;
                #pragma unroll
                for (int v = 0; v < 4; ++v) {
                    int d = qi_s + v - kj; d = d < 0 ? -d : d;
                    float sc = sa[v] * 0.125f - tab[d] + fix;
                    float p = __expf(sc - mrun[v]) * rinv[v];
                    arow[(size_t)v * SS] = p;
                    Ps[wv * 16 + lg * 4 + v][s4 * 16 + ln] = (f16)p;
                }
            }
            #pragma unroll
            for (int ks = 0; ks < 2; ++ks) {
                f16x8 ap = *(const f16x8*)&Ps[wv * 16 + ln][ks * 32 + lg * 8];
                #pragma unroll
                for (int nsub = 0; nsub < 4; ++nsub) {
                    f16x8 bv = *(const f16x8*)&Vt[nsub * 16 + ln][half * 64 + ks * 32 + lg * 8];
                    cacc[nsub] = mfma16(ap, bv, cacc[nsub]);
                }
            }
        }
        __syncthreads();
    }

    #pragma unroll
    for (int nsub = 0; nsub < 4; ++nsub) {
        #pragma unroll
        for (int v = 0; v < 4; ++v) {
            int s = q0 + wv * 16 + lg * 4 + v;
            ctx_out[(size_t)(b * SS + s) * DD + h * DHH + nsub * 16 + ln] = (f16)cacc[nsub][v];
        }
    }
}

// ---------------- host launch ----------------
extern "C" void kernel_launch(void* const* d_in, const int* in_sizes, int n_in,
                              void* d_out, int out_size, void* d_ws, size_t ws_size,
                              hipStream_t stream)
{
    const float* query = (const float*)d_in[0];
    const float* key   = (const float*)d_in[1];
    const float* value = (const float*)d_in[2];
    const float* mask  = (const float*)d_in[3];
    const float* pen   = (const float*)d_in[4];
    // d_in[5] = attention_dropout (0, unused)
    const float* Wq = (const float*)d_in[6];
    const float* Wk = (const float*)d_in[7];
    const float* Wv = (const float*)d_in[8];
    const float* Wo = (const float*)d_in[9];
    const float* bo = (const float*)d_in[10];

    char* ws = (char*)d_ws;
    f16* Wqt   = (f16*)(ws);
    f16* Wkt   = (f16*)(ws + (2ull << 20));
    f16* Wvt   = (f16*)(ws + (4ull << 20));
    f16* Wot   = (f16*)(ws + (6ull << 20));
    f16* qbuf  = (f16*)(ws + (8ull << 20));
    f16* kbuf  = (f16*)(ws + (16ull << 20));
    f16* vtbuf = (f16*)(ws + (24ull << 20));
    f16* ctx   = (f16*)(ws + (32ull << 20));

    float* out_main = (float*)d_out;
    float* attn_out = (float*)d_out + (size_t)BB * SS * DD;

    wtrans_kernel<<<dim3(16, 16, 4), 256, 0, stream>>>(Wq, Wk, Wv, Wo, Wqt, Wkt, Wvt, Wot);
    gemm128<1, 0><<<dim3(8, 32), 256, 0, stream>>>(query, Wqt, nullptr, qbuf);
    gemm128<1, 0><<<dim3(8, 32), 256, 0, stream>>>(key,   Wkt, nullptr, kbuf);
    gemm128<1, 1><<<dim3(8, 32), 256, 0, stream>>>(value, Wvt, nullptr, vtbuf);
    attn_kernel<<<dim3(512), 512, 0, stream>>>(qbuf, kbuf, vtbuf, mask, pen, attn_out, ctx);
    gemm128<0, 2><<<dim3(8, 32), 256, 0, stream>>>(ctx, Wot, bo, out_main);
}

// Round 2
// 343.365 us; speedup vs baseline: 1.2196x; 1.2196x over previous
//
#include <hip/hip_runtime.h>

#define BB 2
#define SS 2048
#define DD 1024
#define HH 16
#define DHH 64

typedef _Float16 f16;
typedef f16 f16x8 __attribute__((ext_vector_type(8)));
typedef f16 f16x4 __attribute__((ext_vector_type(4)));
typedef float f32x4 __attribute__((ext_vector_type(4)));
typedef float fvec4 __attribute__((ext_vector_type(4)));

static __device__ __forceinline__ f32x4 mfma16(f16x8 a, f16x8 b, f32x4 c) {
    return __builtin_amdgcn_mfma_f32_16x16x32_f16(a, b, c, 0, 0, 0);
}

// XOR bank swizzle (T2): col in f16 units, row-stride must be multiple of 64 f16 (128B).
// Applies to byte bits 4..6 -> spreads same-column reads across 8 16B slots.
#define SWZ(r, c) ((c) ^ (((r) & 7) << 3))

// ---------------- weight transpose + f32->f16 convert ----------------
__global__ __launch_bounds__(256) void wtrans_kernel(
    const float* __restrict__ w0, const float* __restrict__ w1,
    const float* __restrict__ w2, const float* __restrict__ w3,
    f16* __restrict__ o0, f16* __restrict__ o1,
    f16* __restrict__ o2, f16* __restrict__ o3)
{
    const float* src; f16* dst;
    switch (blockIdx.z) {
        case 0:  src = w0; dst = o0; break;
        case 1:  src = w1; dst = o1; break;
        case 2:  src = w2; dst = o2; break;
        default: src = w3; dst = o3; break;
    }
    __shared__ float t[64][65];
    const int tid = threadIdx.x;
    const int n0 = blockIdx.x * 64, k0 = blockIdx.y * 64;
    const int r = tid >> 4, c4 = (tid & 15) * 4;
    #pragma unroll
    for (int p = 0; p < 4; ++p) {
        int row = r + p * 16;
        fvec4 v = *(const fvec4*)&src[(size_t)(k0 + row) * DD + n0 + c4];
        #pragma unroll
        for (int j = 0; j < 4; ++j) t[row][c4 + j] = v[j];
    }
    __syncthreads();
    #pragma unroll
    for (int p = 0; p < 4; ++p) {
        int row = r + p * 16;  // n-local
        f16x4 v;
        #pragma unroll
        for (int j = 0; j < 4; ++j) v[j] = (f16)t[c4 + j][row];
        *(f16x4*)&dst[(size_t)(n0 + row) * DD + k0 + c4] = v;
    }
}

// ---------------- fused QKV projection GEMM ----------------
// grid (8, 32, 3): z selects (A, Wt, out). z=0 q, z=1 k, z=2 v (transposed out).
__global__ __launch_bounds__(256) void gemm_qkv(
    const float* __restrict__ Aq, const float* __restrict__ Ak, const float* __restrict__ Av,
    const f16* __restrict__ Wqt, const f16* __restrict__ Wkt, const f16* __restrict__ Wvt,
    f16* __restrict__ oq, f16* __restrict__ ok, f16* __restrict__ ovt)
{
    const int K = DD;
    const float* A; const f16* Bt; f16* C;
    switch (blockIdx.z) {
        case 0:  A = Aq; Bt = Wqt; C = oq; break;
        case 1:  A = Ak; Bt = Wkt; C = ok; break;
        default: A = Av; Bt = Wvt; C = ovt; break;
    }
    const int m0 = blockIdx.y * 128, n0 = blockIdx.x * 128;
    const int tid = threadIdx.x, lane = tid & 63;
    const int wm = (tid >> 7) & 1, wn = (tid >> 6) & 1;
    const int ln = lane & 15, lg = lane >> 4;

    __shared__ f16 As[128 * 64];
    __shared__ f16 Bs[128 * 64];

    f32x4 acc[4][4] = {};

    const int sr = tid >> 3;         // 0..31
    const int sc = (tid & 7) * 8;    // 0..56

    for (int k0 = 0; k0 < K; k0 += 64) {
        #pragma unroll
        for (int p = 0; p < 4; ++p) {
            int row = sr + p * 32;
            const float* s = A + (size_t)(m0 + row) * K + k0 + sc;
            fvec4 x0 = *(const fvec4*)s;
            fvec4 x1 = *(const fvec4*)(s + 4);
            f16x8 v;
            #pragma unroll
            for (int j = 0; j < 4; ++j) { v[j] = (f16)x0[j]; v[j + 4] = (f16)x1[j]; }
            *(f16x8*)&As[row * 64 + SWZ(row, sc)] = v;
            *(f16x8*)&Bs[row * 64 + SWZ(row, sc)] =
                *(const f16x8*)(Bt + (size_t)(n0 + row) * K + k0 + sc);
        }
        __syncthreads();
        #pragma unroll
        for (int ks = 0; ks < 2; ++ks) {
            f16x8 af[4], bf[4];
            #pragma unroll
            for (int i = 0; i < 4; ++i) {
                int ra = wm * 64 + i * 16 + ln, rb = wn * 64 + i * 16 + ln;
                int cc = ks * 32 + lg * 8;
                af[i] = *(const f16x8*)&As[ra * 64 + SWZ(ra, cc)];
                bf[i] = *(const f16x8*)&Bs[rb * 64 + SWZ(rb, cc)];
            }
            #pragma unroll
            for (int i = 0; i < 4; ++i)
                #pragma unroll
                for (int j = 0; j < 4; ++j)
                    acc[i][j] = mfma16(af[i], bf[j], acc[i][j]);
        }
        __syncthreads();
    }

    const int vmode = (blockIdx.z == 2);
    #pragma unroll
    for (int i = 0; i < 4; ++i) {
        #pragma unroll
        for (int j = 0; j < 4; ++j) {
            if (vmode) {
                int m = m0 + wm * 64 + i * 16 + lg * 4;
                int n = n0 + wn * 64 + j * 16 + ln;
                int b = m >> 11, s = m & (SS - 1);
                int h = n >> 6, dh = n & 63;
                f16x4 v4;
                #pragma unroll
                for (int v = 0; v < 4; ++v) v4[v] = (f16)acc[i][j][v];
                *(f16x4*)&C[((size_t)((b * HH + h) * DHH + dh)) * SS + s] = v4;
            } else {
                #pragma unroll
                for (int v = 0; v < 4; ++v) {
                    int m = m0 + wm * 64 + i * 16 + lg * 4 + v;
                    int n = n0 + wn * 64 + j * 16 + ln;
                    int b = m >> 11, s = m & (SS - 1);
                    int h = n >> 6, dh = n & 63;
                    C[((size_t)((b * HH + h) * SS + s)) * DHH + dh] = (f16)acc[i][j][v];
                }
            }
        }
    }
}

// ---------------- final projection GEMM (f16 A, f32 out + bias) ----------------
__global__ __launch_bounds__(256) void gemm_out(
    const f16* __restrict__ A, const f16* __restrict__ Bt,
    const float* __restrict__ bias, float* __restrict__ C)
{
    const int K = DD;
    const int m0 = blockIdx.y * 128, n0 = blockIdx.x * 128;
    const int tid = threadIdx.x, lane = tid & 63;
    const int wm = (tid >> 7) & 1, wn = (tid >> 6) & 1;
    const int ln = lane & 15, lg = lane >> 4;

    __shared__ f16 As[128 * 64];
    __shared__ f16 Bs[128 * 64];

    f32x4 acc[4][4] = {};

    const int sr = tid >> 3, sc = (tid & 7) * 8;

    for (int k0 = 0; k0 < K; k0 += 64) {
        #pragma unroll
        for (int p = 0; p < 4; ++p) {
            int row = sr + p * 32;
            *(f16x8*)&As[row * 64 + SWZ(row, sc)] =
                *(const f16x8*)(A + (size_t)(m0 + row) * K + k0 + sc);
            *(f16x8*)&Bs[row * 64 + SWZ(row, sc)] =
                *(const f16x8*)(Bt + (size_t)(n0 + row) * K + k0 + sc);
        }
        __syncthreads();
        #pragma unroll
        for (int ks = 0; ks < 2; ++ks) {
            f16x8 af[4], bf[4];
            #pragma unroll
            for (int i = 0; i < 4; ++i) {
                int ra = wm * 64 + i * 16 + ln, rb = wn * 64 + i * 16 + ln;
                int cc = ks * 32 + lg * 8;
                af[i] = *(const f16x8*)&As[ra * 64 + SWZ(ra, cc)];
                bf[i] = *(const f16x8*)&Bs[rb * 64 + SWZ(rb, cc)];
            }
            #pragma unroll
            for (int i = 0; i < 4; ++i)
                #pragma unroll
                for (int j = 0; j < 4; ++j)
                    acc[i][j] = mfma16(af[i], bf[j], acc[i][j]);
        }
        __syncthreads();
    }

    #pragma unroll
    for (int i = 0; i < 4; ++i)
        #pragma unroll
        for (int j = 0; j < 4; ++j)
            #pragma unroll
            for (int v = 0; v < 4; ++v) {
                int m = m0 + wm * 64 + i * 16 + lg * 4 + v;
                int n = n0 + wn * 64 + j * 16 + ln;
                C[(size_t)m * DD + n] = acc[i][j][v] + bias[n];
            }
}

// ---------------- fused attention ----------------
__global__ __launch_bounds__(512) void attn_kernel(
    const f16* __restrict__ qg, const f16* __restrict__ kg, const f16* __restrict__ vtg,
    const float* __restrict__ maskg, const float* __restrict__ peng,
    float* __restrict__ attn_out, f16* __restrict__ ctx_out)
{
    const int bid = blockIdx.x;
    const int wg = (bid & 7) * 64 + (bid >> 3);   // bijective XCD swizzle (512 % 8 == 0)
    const int bh = wg >> 4;
    const int b = bh >> 4, h = bh & 15;
    const int q0 = (wg & 15) * 128;

    const int tid = threadIdx.x, lane = tid & 63, wv = tid >> 6;
    const int ln = lane & 15, lg = lane >> 4;

    __shared__ f16 Ks[128 * 64];
    __shared__ f16 Vt[64 * 128];
    __shared__ f16 Ps[128 * 64];
    __shared__ float tab[SS];
    __shared__ float mrow[SS];

    for (int i = tid; i < SS; i += 512) {
        tab[i]  = log1pf(peng[i]);
        mrow[i] = maskg[b * SS + i] * (-1e9f);
    }

    const f16* qbase = qg + ((size_t)bh * SS + q0 + wv * 16 + ln) * DHH;
    f16x8 aq0 = *(const f16x8*)(qbase + lg * 8);
    f16x8 aq1 = *(const f16x8*)(qbase + 32 + lg * 8);

    __syncthreads();

    const int qi_s = q0 + wv * 16 + lg * 4;

    float mrun[4], lrun[4];
    #pragma unroll
    for (int v = 0; v < 4; ++v) { mrun[v] = -3e38f; lrun[v] = 0.f; }

    const int str = tid >> 3,  stc = (tid & 7) * 8;    // K staging
    const int vtr = tid >> 4,  vtc = (tid & 15) * 8;   // Vt staging

    // ---- pass 1: online (m, l) ----
    for (int kt = 0; kt < 16; ++kt) {
        const f16* ksrc = kg + ((size_t)bh * SS + kt * 128) * DHH;
        #pragma unroll
        for (int p = 0; p < 2; ++p) {
            int row = str + p * 64;
            *(f16x8*)&Ks[row * 64 + SWZ(row, stc)] =
                *(const f16x8*)(ksrc + (size_t)row * DHH + stc);
        }
        __syncthreads();

        f32x4 sfr[8];
        #pragma unroll
        for (int sub = 0; sub < 8; ++sub) {
            int kr = sub * 16 + ln;
            f32x4 sa = {0.f, 0.f, 0.f, 0.f};
            sa = mfma16(aq0, *(const f16x8*)&Ks[kr * 64 + SWZ(kr, lg * 8)], sa);
            sa = mfma16(aq1, *(const f16x8*)&Ks[kr * 64 + SWZ(kr, 32 + lg * 8)], sa);
            const int kj = kt * 128 + kr;
            const float fix = mrow[kj];
            #pragma unroll
            for (int v = 0; v < 4; ++v) {
                int d = qi_s + v - kj; d = d < 0 ? -d : d;
                sa[v] = sa[v] * 0.125f - tab[d] + fix;
            }
            sfr[sub] = sa;
        }
        #pragma unroll
        for (int v = 0; v < 4; ++v) {
            float mx = sfr[0][v];
            #pragma unroll
            for (int sub = 1; sub < 8; ++sub) mx = fmaxf(mx, sfr[sub][v]);
            #pragma unroll
            for (int off = 1; off < 16; off <<= 1) mx = fmaxf(mx, __shfl_xor(mx, off));
            float mnew = fmaxf(mrun[v], mx);
            float sum = 0.f;
            #pragma unroll
            for (int sub = 0; sub < 8; ++sub) sum += __expf(sfr[sub][v] - mnew);
            #pragma unroll
            for (int off = 1; off < 16; off <<= 1) sum += __shfl_xor(sum, off);
            lrun[v] = lrun[v] * __expf(mrun[v] - mnew) + sum;
            mrun[v] = mnew;
        }
        __syncthreads();
    }

    float rinv[4];
    #pragma unroll
    for (int v = 0; v < 4; ++v) rinv[v] = 1.f / lrun[v];

    f32x4 cacc[4] = {};

    // ---- pass 2: recompute, normalize, store attn, PV ----
    for (int kt = 0; kt < 16; ++kt) {
        const f16* ksrc = kg + ((size_t)bh * SS + kt * 128) * DHH;
        #pragma unroll
        for (int p = 0; p < 2; ++p) {
            int row = str + p * 64;
            *(f16x8*)&Ks[row * 64 + SWZ(row, stc)] =
                *(const f16x8*)(ksrc + (size_t)row * DHH + stc);
        }
        const f16* vsrc = vtg + (size_t)bh * DHH * SS + kt * 128;
        #pragma unroll
        for (int p = 0; p < 2; ++p) {
            int row = vtr + p * 32;
            *(f16x8*)&Vt[row * 128 + SWZ(row, vtc)] =
                *(const f16x8*)(vsrc + (size_t)row * SS + vtc);
        }
        __syncthreads();

        #pragma unroll
        for (int half = 0; half < 2; ++half) {
            #pragma unroll
            for (int s4 = 0; s4 < 4; ++s4) {
                const int sub = half * 4 + s4;
                int kr = sub * 16 + ln;
                f32x4 sa = {0.f, 0.f, 0.f, 0.f};
                sa = mfma16(aq0, *(const f16x8*)&Ks[kr * 64 + SWZ(kr, lg * 8)], sa);
                sa = mfma16(aq1, *(const f16x8*)&Ks[kr * 64 + SWZ(kr, 32 + lg * 8)], sa);
                const int kj = kt * 128 + kr;
                const float fix = mrow[kj];
                float* arow = attn_out + (size_t)(bh * SS + q0 + wv * 16 + lg * 4) * SS + kj;
                #pragma unroll
                for (int v = 0; v < 4; ++v) {
                    int d = qi_s + v - kj; d = d < 0 ? -d : d;
                    float sc = sa[v] * 0.125f - tab[d] + fix;
                    float p = __expf(sc - mrun[v]) * rinv[v];
                    __builtin_nontemporal_store(p, arow + (size_t)v * SS);
                    int pr = wv * 16 + lg * 4 + v;
                    Ps[pr * 64 + SWZ(pr, s4 * 16 + ln)] = (f16)p;
                }
            }
            #pragma unroll
            for (int ks = 0; ks < 2; ++ks) {
                int prr = wv * 16 + ln;
                f16x8 ap = *(const f16x8*)&Ps[prr * 64 + SWZ(prr, ks * 32 + lg * 8)];
                #pragma unroll
                for (int nsub = 0; nsub < 4; ++nsub) {
                    int vr = nsub * 16 + ln;
                    f16x8 bv = *(const f16x8*)&Vt[vr * 128 + SWZ(vr, half * 64 + ks * 32 + lg * 8)];
                    cacc[nsub] = mfma16(ap, bv, cacc[nsub]);
                }
            }
        }
        __syncthreads();
    }

    #pragma unroll
    for (int nsub = 0; nsub < 4; ++nsub) {
        #pragma unroll
        for (int v = 0; v < 4; ++v) {
            int s = q0 + wv * 16 + lg * 4 + v;
            ctx_out[(size_t)(b * SS + s) * DD + h * DHH + nsub * 16 + ln] = (f16)cacc[nsub][v];
        }
    }
}

// ---------------- host launch ----------------
extern "C" void kernel_launch(void* const* d_in, const int* in_sizes, int n_in,
                              void* d_out, int out_size, void* d_ws, size_t ws_size,
                              hipStream_t stream)
{
    const float* query = (const float*)d_in[0];
    const float* key   = (const float*)d_in[1];
    const float* value = (const float*)d_in[2];
    const float* mask  = (const float*)d_in[3];
    const float* pen   = (const float*)d_in[4];
    const float* Wq = (const float*)d_in[6];
    const float* Wk = (const float*)d_in[7];
    const float* Wv = (const float*)d_in[8];
    const float* Wo = (const float*)d_in[9];
    const float* bo = (const float*)d_in[10];

    char* ws = (char*)d_ws;
    f16* Wqt   = (f16*)(ws);
    f16* Wkt   = (f16*)(ws + (2ull << 20));
    f16* Wvt   = (f16*)(ws + (4ull << 20));
    f16* Wot   = (f16*)(ws + (6ull << 20));
    f16* qbuf  = (f16*)(ws + (8ull << 20));
    f16* kbuf  = (f16*)(ws + (16ull << 20));
    f16* vtbuf = (f16*)(ws + (24ull << 20));
    f16* ctx   = (f16*)(ws + (32ull << 20));

    float* out_main = (float*)d_out;
    float* attn_out = (float*)d_out + (size_t)BB * SS * DD;

    wtrans_kernel<<<dim3(16, 16, 4), 256, 0, stream>>>(Wq, Wk, Wv, Wo, Wqt, Wkt, Wvt, Wot);
    gemm_qkv<<<dim3(8, 32, 3), 256, 0, stream>>>(query, key, value, Wqt, Wkt, Wvt, qbuf, kbuf, vtbuf);
    attn_kernel<<<dim3(512), 512, 0, stream>>>(qbuf, kbuf, vtbuf, mask, pen, attn_out, ctx);
    gemm_out<<<dim3(8, 32), 256, 0, stream>>>(ctx, Wot, bo, out_main);
}